// Round 1
// baseline (403.044 us; speedup 1.0000x reference)
//
#include <hip/hip_runtime.h>
#include <cstdint>
#include <cstddef>

#define NN 8192
#define FIN 128
#define FOUT 64
#define BM 32
#define BN 64
#define JSPLIT 4
#define JCH (NN / JSPLIT)     // 2048 columns per block
#define NCHUNK (JCH / BN)     // 32 chunks
#define LDP 72                // padded LDS row (bf16 elems): 144 B, 16B-aligned, breaks pow2 bank stride

typedef __bf16 bf16x8 __attribute__((ext_vector_type(8)));
typedef unsigned short u16x8 __attribute__((ext_vector_type(8)));
typedef float f32x4 __attribute__((ext_vector_type(4)));

__device__ __forceinline__ unsigned short f2bf(float f) {
    unsigned u = __float_as_uint(f);
    u += 0x7FFFu + ((u >> 16) & 1u);   // RNE
    return (unsigned short)(u >> 16);
}
__device__ __forceinline__ float bf2f(unsigned short b) {
    return __uint_as_float(((unsigned)b) << 16);
}

// ---------------------------------------------------------------------------
// Kernel 1: prep. Per block: 32 rows.
//  - stage W transposed in LDS
//  - wa1 = W@a1, wa2 = W@a2 (redundant per block, cheap)
//  - s1[i] = x_i . wa1, s2[i] = x_i . wa2   (fp32 exact path)
//  - Ht[t][i] = bf16( (x@W)[i][t] ) via MFMA (bf16 inputs, fp32 acc)
//  - global max of s2 via order-encoded atomicMax
// ---------------------------------------------------------------------------
__global__ __launch_bounds__(256) void gat_prep(
    const float* __restrict__ x, const float* __restrict__ W,
    const float* __restrict__ a, float* __restrict__ s1,
    float* __restrict__ s2, unsigned short* __restrict__ Ht,
    unsigned int* __restrict__ s2max_enc)
{
    __shared__ __align__(16) float Wt[FOUT][FIN + 4];  // W transposed: Wt[t][k]
    __shared__ float wa1[FIN], wa2[FIN];
    __shared__ float ash[2 * FOUT];
    __shared__ float s2sh[BM];

    const int tid = threadIdx.x;
    const int i0 = blockIdx.x * BM;

    // stage W transposed (coalesced global read)
    for (int it = 0; it < 32; ++it) {
        int idx = it * 256 + tid;          // 0..8191
        int k = idx >> 6, t = idx & 63;
        Wt[t][k] = W[idx];
    }
    if (tid < 2 * FOUT) ash[tid] = a[tid];
    __syncthreads();

    // wa = W @ a halves
    if (tid < FIN) {
        int k = tid;
        float acc = 0.f;
        #pragma unroll 8
        for (int t = 0; t < FOUT; ++t) acc = fmaf(Wt[t][k], ash[t], acc);
        wa1[k] = acc;
    } else {
        int k = tid - FIN;
        float acc = 0.f;
        #pragma unroll 8
        for (int t = 0; t < FOUT; ++t) acc = fmaf(Wt[t][k], ash[FOUT + t], acc);
        wa2[k] = acc;
    }
    __syncthreads();

    // s1, s2: 8 threads per row, 16 floats each
    {
        int r = tid >> 3;          // 0..31
        int seg = tid & 7;
        const float* xp = x + (size_t)(i0 + r) * FIN + seg * 16;
        float d1 = 0.f, d2 = 0.f;
        #pragma unroll
        for (int m = 0; m < 16; ++m) {
            float xv = xp[m];
            d1 = fmaf(xv, wa1[seg * 16 + m], d1);
            d2 = fmaf(xv, wa2[seg * 16 + m], d2);
        }
        #pragma unroll
        for (int mk = 1; mk < 8; mk <<= 1) {
            d1 += __shfl_xor(d1, mk);
            d2 += __shfl_xor(d2, mk);
        }
        if (seg == 0) {
            s1[i0 + r] = d1;
            s2[i0 + r] = d2;
            s2sh[r] = d2;
        }
    }

    // Ht = (x@W)^T bf16 via MFMA 16x16x32
    {
        const int lane = tid & 63;
        const int wv = tid >> 6;
        const int ih = wv & 1, nh = wv >> 1;
        const int m = lane & 15, quad = lane >> 4;
        f32x4 hacc0 = {0.f, 0.f, 0.f, 0.f};
        f32x4 hacc1 = {0.f, 0.f, 0.f, 0.f};
        const float* xrow = x + (size_t)(i0 + ih * 16 + m) * FIN + quad * 8;
        #pragma unroll
        for (int ks = 0; ks < 4; ++ks) {
            const float* xp = xrow + ks * 32;
            u16x8 ua;
            #pragma unroll
            for (int jj = 0; jj < 8; ++jj) ua[jj] = f2bf(xp[jj]);
            bf16x8 af = __builtin_bit_cast(bf16x8, ua);
            {
                const float* wp = &Wt[nh * 32 + m][ks * 32 + quad * 8];
                u16x8 ub;
                #pragma unroll
                for (int jj = 0; jj < 8; ++jj) ub[jj] = f2bf(wp[jj]);
                bf16x8 bfr = __builtin_bit_cast(bf16x8, ub);
                hacc0 = __builtin_amdgcn_mfma_f32_16x16x32_bf16(af, bfr, hacc0, 0, 0, 0);
            }
            {
                const float* wp = &Wt[nh * 32 + 16 + m][ks * 32 + quad * 8];
                u16x8 ub;
                #pragma unroll
                for (int jj = 0; jj < 8; ++jj) ub[jj] = f2bf(wp[jj]);
                bf16x8 bfr = __builtin_bit_cast(bf16x8, ub);
                hacc1 = __builtin_amdgcn_mfma_f32_16x16x32_bf16(af, bfr, hacc1, 0, 0, 0);
            }
        }
        // C layout: col = lane&15 (n), row = quad*4+reg (i)
        #pragma unroll
        for (int reg = 0; reg < 4; ++reg) {
            int irow = i0 + ih * 16 + quad * 4 + reg;
            int t0 = nh * 32 + m;
            Ht[(size_t)t0 * NN + irow] = f2bf(hacc0[reg]);
            Ht[(size_t)(t0 + 16) * NN + irow] = f2bf(hacc1[reg]);
        }
    }
    __syncthreads();
    if (tid == 0) {
        float mx = s2sh[0];
        #pragma unroll
        for (int r = 1; r < BM; ++r) mx = fmaxf(mx, s2sh[r]);
        unsigned ub = __float_as_uint(mx);
        unsigned enc = (ub & 0x80000000u) ? ~ub : (ub | 0x80000000u);
        atomicMax(s2max_enc, enc);
    }
}

// ---------------------------------------------------------------------------
// Kernel 2: fused masked-softmax + PV matmul, fixed reference M_i (no online
// rescale), j-split 4 ways. One block: 32 rows x 2048 j, streamed in 64-j
// chunks with register prefetch across the barrier.
// ---------------------------------------------------------------------------
__global__ __launch_bounds__(256, 4) void gat_attn(
    const int* __restrict__ adj, const float* __restrict__ s1,
    const float* __restrict__ s2, const unsigned short* __restrict__ Ht,
    const unsigned int* __restrict__ s2max_enc,
    float* __restrict__ pacc, float* __restrict__ pl)
{
    __shared__ __align__(16) unsigned short p_lds[BM][LDP];
    __shared__ __align__(16) unsigned short ht_lds[FOUT][LDP];
    __shared__ float s1v[BM], Mv[BM], lrow[BM];

    const int tid = threadIdx.x;
    const int bx = blockIdx.x;
    const int r = bx >> 2;
    const int js = bx & 3;
    const int i0 = r * BM;
    const int j0 = js * JCH;

    {
        unsigned u = *s2max_enc;
        float S2MAX = (u & 0x80000000u) ? __uint_as_float(u ^ 0x80000000u)
                                        : __uint_as_float(~u);
        if (tid < BM) {
            float s = s1[i0 + tid];
            s1v[tid] = s;
            Mv[tid] = fmaxf(0.f, s + S2MAX);  // upper bound of row max of e
            lrow[tid] = 0.f;
        }
    }
    __syncthreads();

    const int li = tid >> 4;          // 0..15 (adj row within pass)
    const int jg = (tid & 15) * 4;    // adj col group
    const int th = tid >> 3;          // 0..31 (Ht row)
    const int jh = (tid & 7) * 8;     // Ht col group

    const int* adjp0 = adj + (size_t)(i0 + li) * NN + j0 + jg;
    const int* adjp1 = adjp0 + 16 * NN;
    const unsigned short* htp0 = Ht + (size_t)th * NN + j0 + jh;
    const unsigned short* htp1 = htp0 + 32 * NN;

    const int lane = tid & 63;
    const int wv = tid >> 6;
    const int ih = wv & 1, nh = wv >> 1;
    const int cm = lane & 15, quad = lane >> 4;

    f32x4 acc0 = {0.f, 0.f, 0.f, 0.f};
    f32x4 acc1 = {0.f, 0.f, 0.f, 0.f};

    // prologue loads (chunk 0)
    int4 ca0 = *(const int4*)adjp0;
    int4 ca1 = *(const int4*)adjp1;
    uint4 ch0 = *(const uint4*)htp0;
    uint4 ch1 = *(const uint4*)htp1;

    const float s1a = s1v[li], Ma = Mv[li];
    const float s1b = s1v[li + 16], Mb = Mv[li + 16];

    for (int c = 0; c < NCHUNK; ++c) {
        // register prefetch for next chunk (survives s_barrier: reg-destined)
        const int cn = (c + 1 < NCHUNK) ? (c + 1) : c;
        int4 na0 = *(const int4*)(adjp0 + cn * BN);
        int4 na1 = *(const int4*)(adjp1 + cn * BN);
        uint4 nh0 = *(const uint4*)(htp0 + cn * BN);
        uint4 nh1 = *(const uint4*)(htp1 + cn * BN);

        __syncthreads();   // previous chunk's LDS reads complete

        // stage Ht chunk
        *(uint4*)&ht_lds[th][jh] = ch0;
        *(uint4*)&ht_lds[th + 32][jh] = ch1;

        // compute p (bf16) + row-sum l
        {
            const float4 s2q = *(const float4*)(s2 + j0 + c * BN + jg);
            const int* av0 = (const int*)&ca0;
            const int* av1 = (const int*)&ca1;
            const float* s2v = (const float*)&s2q;
            unsigned short qa[4], qb[4];
            float psA = 0.f, psB = 0.f;
            #pragma unroll
            for (int jj = 0; jj < 4; ++jj) {
                float s2x = s2v[jj];
                float eA = fmaxf(s1a + s2x, 0.f);
                float pA = (av0[jj] > 0) ? __expf(eA - Ma) : 0.f;
                qa[jj] = f2bf(pA);
                psA += bf2f(qa[jj]);
                float eB = fmaxf(s1b + s2x, 0.f);
                float pB = (av1[jj] > 0) ? __expf(eB - Mb) : 0.f;
                qb[jj] = f2bf(pB);
                psB += bf2f(qb[jj]);
            }
            *(ushort4*)&p_lds[li][jg]      = make_ushort4(qa[0], qa[1], qa[2], qa[3]);
            *(ushort4*)&p_lds[li + 16][jg] = make_ushort4(qb[0], qb[1], qb[2], qb[3]);
            #pragma unroll
            for (int mk = 1; mk < 16; mk <<= 1) {
                psA += __shfl_xor(psA, mk);
                psB += __shfl_xor(psB, mk);
            }
            if ((tid & 15) == 0) {
                lrow[li] += psA;
                lrow[li + 16] += psB;
            }
        }
        __syncthreads();

        // PV MFMA: per wave, 16 rows (ih) x 32 cols (nh), K=64 in 2 steps
        #pragma unroll
        for (int ks = 0; ks < 2; ++ks) {
            bf16x8 af  = *(const bf16x8*)&p_lds[ih * 16 + cm][ks * 32 + quad * 8];
            bf16x8 bf0 = *(const bf16x8*)&ht_lds[nh * 32 + cm][ks * 32 + quad * 8];
            bf16x8 bf1 = *(const bf16x8*)&ht_lds[nh * 32 + 16 + cm][ks * 32 + quad * 8];
            acc0 = __builtin_amdgcn_mfma_f32_16x16x32_bf16(af, bf0, acc0, 0, 0, 0);
            acc1 = __builtin_amdgcn_mfma_f32_16x16x32_bf16(af, bf1, acc1, 0, 0, 0);
        }

        ca0 = na0; ca1 = na1; ch0 = nh0; ch1 = nh1;
    }
    __syncthreads();

    // write partial acc / l
    #pragma unroll
    for (int reg = 0; reg < 4; ++reg) {
        int irow = i0 + ih * 16 + quad * 4 + reg;
        int n0 = nh * 32 + cm;
        pacc[((size_t)js * NN + irow) * FOUT + n0]      = acc0[reg];
        pacc[((size_t)js * NN + irow) * FOUT + n0 + 16] = acc1[reg];
    }
    if (tid < BM) pl[(size_t)js * NN + i0 + tid] = lrow[tid];
}

// ---------------------------------------------------------------------------
// Kernel 3: combine j-split partials: out = sum(acc) / sum(l)
// ---------------------------------------------------------------------------
__global__ __launch_bounds__(256) void gat_combine(
    const float* __restrict__ pacc, const float* __restrict__ pl,
    float* __restrict__ out)
{
    int idx = blockIdx.x * 256 + threadIdx.x;   // over NN*FOUT
    int i = idx >> 6;
    float s = 0.f, l = 0.f;
    #pragma unroll
    for (int js = 0; js < JSPLIT; ++js) {
        s += pacc[(size_t)js * NN * FOUT + idx];
        l += pl[(size_t)js * NN + i];
    }
    out[idx] = s / l;
}

// ---------------------------------------------------------------------------
extern "C" void kernel_launch(void* const* d_in, const int* in_sizes, int n_in,
                              void* d_out, int out_size, void* d_ws, size_t ws_size,
                              hipStream_t stream) {
    const float* x   = (const float*)d_in[0];
    const int*   adj = (const int*)d_in[1];
    const float* W   = (const float*)d_in[2];
    const float* a   = (const float*)d_in[3];
    float* out = (float*)d_out;

    char* ws = (char*)d_ws;
    float* s1             = (float*)(ws);                         // 32 KB
    float* s2             = (float*)(ws + 32768);                 // 32 KB
    unsigned int* s2enc   = (unsigned int*)(ws + 65536);          // 4 B (padded to 1 KB)
    unsigned short* Ht    = (unsigned short*)(ws + 66560);        // 1 MiB
    float* pacc           = (float*)(ws + 66560 + 1048576);       // 8 MiB
    float* pl             = (float*)(ws + 66560 + 1048576 + 8388608); // 128 KB

    hipMemsetAsync(s2enc, 0, 4, stream);
    gat_prep<<<NN / BM, 256, 0, stream>>>(x, W, a, s1, s2, Ht, s2enc);
    gat_attn<<<(NN / BM) * JSPLIT, 256, 0, stream>>>(adj, s1, s2, Ht, s2enc, pacc, pl);
    gat_combine<<<NN * FOUT / 256, 256, 0, stream>>>(pacc, pl, out);
}

// Round 2
// 402.489 us; speedup vs baseline: 1.0014x; 1.0014x over previous
//
#include <hip/hip_runtime.h>
#include <cstdint>
#include <cstddef>

#define NN 8192
#define FIN 128
#define FOUT 64
#define BM 32
#define BN 64
#define JSPLIT 4
#define JCH (NN / JSPLIT)     // 2048 columns per block
#define NCHUNK (JCH / BN)     // 32 chunks
#define LDP 72                // padded LDS row (bf16 elems): 144 B, breaks pow2 bank stride

typedef __bf16 bf16x8 __attribute__((ext_vector_type(8)));
typedef unsigned short u16x8 __attribute__((ext_vector_type(8)));
typedef float f32x4 __attribute__((ext_vector_type(4)));

__device__ __forceinline__ unsigned short f2bf(float f) {
    unsigned u = __float_as_uint(f);
    u += 0x7FFFu + ((u >> 16) & 1u);   // RNE
    return (unsigned short)(u >> 16);
}
__device__ __forceinline__ float bf2f(unsigned short b) {
    return __uint_as_float(((unsigned)b) << 16);
}

// ---------------------------------------------------------------------------
// Kernel 1: prep (unchanged from R0 — passed, small).
// ---------------------------------------------------------------------------
__global__ __launch_bounds__(256) void gat_prep(
    const float* __restrict__ x, const float* __restrict__ W,
    const float* __restrict__ a, float* __restrict__ s1,
    float* __restrict__ s2, unsigned short* __restrict__ Ht,
    unsigned int* __restrict__ s2max_enc)
{
    __shared__ __align__(16) float Wt[FOUT][FIN + 4];  // W transposed: Wt[t][k]
    __shared__ float wa1[FIN], wa2[FIN];
    __shared__ float ash[2 * FOUT];
    __shared__ float s2sh[BM];

    const int tid = threadIdx.x;
    const int i0 = blockIdx.x * BM;

    for (int it = 0; it < 32; ++it) {
        int idx = it * 256 + tid;          // 0..8191
        int k = idx >> 6, t = idx & 63;
        Wt[t][k] = W[idx];
    }
    if (tid < 2 * FOUT) ash[tid] = a[tid];
    __syncthreads();

    if (tid < FIN) {
        int k = tid;
        float acc = 0.f;
        #pragma unroll 8
        for (int t = 0; t < FOUT; ++t) acc = fmaf(Wt[t][k], ash[t], acc);
        wa1[k] = acc;
    } else {
        int k = tid - FIN;
        float acc = 0.f;
        #pragma unroll 8
        for (int t = 0; t < FOUT; ++t) acc = fmaf(Wt[t][k], ash[FOUT + t], acc);
        wa2[k] = acc;
    }
    __syncthreads();

    {
        int r = tid >> 3;          // 0..31
        int seg = tid & 7;
        const float* xp = x + (size_t)(i0 + r) * FIN + seg * 16;
        float d1 = 0.f, d2 = 0.f;
        #pragma unroll
        for (int m = 0; m < 16; ++m) {
            float xv = xp[m];
            d1 = fmaf(xv, wa1[seg * 16 + m], d1);
            d2 = fmaf(xv, wa2[seg * 16 + m], d2);
        }
        #pragma unroll
        for (int mk = 1; mk < 8; mk <<= 1) {
            d1 += __shfl_xor(d1, mk);
            d2 += __shfl_xor(d2, mk);
        }
        if (seg == 0) {
            s1[i0 + r] = d1;
            s2[i0 + r] = d2;
            s2sh[r] = d2;
        }
    }

    {
        const int lane = tid & 63;
        const int wv = tid >> 6;
        const int ih = wv & 1, nh = wv >> 1;
        const int m = lane & 15, quad = lane >> 4;
        f32x4 hacc0 = {0.f, 0.f, 0.f, 0.f};
        f32x4 hacc1 = {0.f, 0.f, 0.f, 0.f};
        const float* xrow = x + (size_t)(i0 + ih * 16 + m) * FIN + quad * 8;
        #pragma unroll
        for (int ks = 0; ks < 4; ++ks) {
            const float* xp = xrow + ks * 32;
            u16x8 ua;
            #pragma unroll
            for (int jj = 0; jj < 8; ++jj) ua[jj] = f2bf(xp[jj]);
            bf16x8 af = __builtin_bit_cast(bf16x8, ua);
            {
                const float* wp = &Wt[nh * 32 + m][ks * 32 + quad * 8];
                u16x8 ub;
                #pragma unroll
                for (int jj = 0; jj < 8; ++jj) ub[jj] = f2bf(wp[jj]);
                bf16x8 bfr = __builtin_bit_cast(bf16x8, ub);
                hacc0 = __builtin_amdgcn_mfma_f32_16x16x32_bf16(af, bfr, hacc0, 0, 0, 0);
            }
            {
                const float* wp = &Wt[nh * 32 + 16 + m][ks * 32 + quad * 8];
                u16x8 ub;
                #pragma unroll
                for (int jj = 0; jj < 8; ++jj) ub[jj] = f2bf(wp[jj]);
                bf16x8 bfr = __builtin_bit_cast(bf16x8, ub);
                hacc1 = __builtin_amdgcn_mfma_f32_16x16x32_bf16(af, bfr, hacc1, 0, 0, 0);
            }
        }
        #pragma unroll
        for (int reg = 0; reg < 4; ++reg) {
            int irow = i0 + ih * 16 + quad * 4 + reg;
            int t0 = nh * 32 + m;
            Ht[(size_t)t0 * NN + irow] = f2bf(hacc0[reg]);
            Ht[(size_t)(t0 + 16) * NN + irow] = f2bf(hacc1[reg]);
        }
    }
    __syncthreads();
    if (tid == 0) {
        float mx = s2sh[0];
        #pragma unroll
        for (int r = 1; r < BM; ++r) mx = fmaxf(mx, s2sh[r]);
        unsigned ub = __float_as_uint(mx);
        unsigned enc = (ub & 0x80000000u) ? ~ub : (ub | 0x80000000u);
        atomicMax(s2max_enc, enc);
    }
}

// ---------------------------------------------------------------------------
// Kernel 2: fused masked-softmax + PV matmul.
// R1 changes: double-buffered LDS (ONE barrier/chunk), s2 strip staged in LDS
// once, l-reduction deferred to registers (single shuffle-reduce at end).
// ---------------------------------------------------------------------------
__global__ __launch_bounds__(256, 4) void gat_attn(
    const int* __restrict__ adj, const float* __restrict__ s1,
    const float* __restrict__ s2, const unsigned short* __restrict__ Ht,
    const unsigned int* __restrict__ s2max_enc,
    float* __restrict__ pacc, float* __restrict__ pl)
{
    __shared__ __align__(16) unsigned short p_lds[2][BM][LDP];     // 9.2 KB
    __shared__ __align__(16) unsigned short ht_lds[2][FOUT][LDP];  // 18.4 KB
    __shared__ __align__(16) float s2sh[JCH];                      // 8 KB
    __shared__ float s1v[BM], Mv[BM];

    const int tid = threadIdx.x;
    const int bx = blockIdx.x;
    const int r = bx >> 2;
    const int js = bx & 3;
    const int i0 = r * BM;
    const int j0 = js * JCH;

    const int li = tid >> 4;          // 0..15 (adj row within pass)
    const int jg = (tid & 15) * 4;    // adj col group
    const int th = tid >> 3;          // 0..31 (Ht row)
    const int jh = (tid & 7) * 8;     // Ht col group

    const int* adjp0 = adj + (size_t)(i0 + li) * NN + j0 + jg;
    const int* adjp1 = adjp0 + 16 * NN;
    const unsigned short* htp0 = Ht + (size_t)th * NN + j0 + jh;
    const unsigned short* htp1 = htp0 + 32 * NN;

    // prologue global loads (chunk 0) — issue before any LDS dependency
    int4 ca0 = *(const int4*)adjp0;
    int4 ca1 = *(const int4*)adjp1;
    uint4 ch0 = *(const uint4*)htp0;
    uint4 ch1 = *(const uint4*)htp1;

    // stage s2 strip + per-row s1/M
    {
        #pragma unroll
        for (int it = 0; it < 2; ++it) {
            int idx = (it * 256 + tid) * 4;
            *(float4*)&s2sh[idx] = *(const float4*)(s2 + j0 + idx);
        }
        unsigned u = *s2max_enc;
        float S2MAX = (u & 0x80000000u) ? __uint_as_float(u ^ 0x80000000u)
                                        : __uint_as_float(~u);
        if (tid < BM) {
            float s = s1[i0 + tid];
            s1v[tid] = s;
            Mv[tid] = fmaxf(0.f, s + S2MAX);  // upper bound of row max of e
        }
    }
    __syncthreads();

    const int lane = tid & 63;
    const int wv = tid >> 6;
    const int ih = wv & 1, nh = wv >> 1;
    const int cm = lane & 15, quad = lane >> 4;

    f32x4 acc0 = {0.f, 0.f, 0.f, 0.f};
    f32x4 acc1 = {0.f, 0.f, 0.f, 0.f};
    float psA = 0.f, psB = 0.f;       // deferred l partial sums (registers)

    const float s1a = s1v[li], Ma = Mv[li];
    const float s1b = s1v[li + 16], Mb = Mv[li + 16];

    for (int c = 0; c < NCHUNK; ++c) {
        const int buf = c & 1;

        // register prefetch for next chunk
        const int cn = (c + 1 < NCHUNK) ? (c + 1) : c;
        int4 na0 = *(const int4*)(adjp0 + cn * BN);
        int4 na1 = *(const int4*)(adjp1 + cn * BN);
        uint4 nh0 = *(const uint4*)(htp0 + cn * BN);
        uint4 nh1 = *(const uint4*)(htp1 + cn * BN);

        // stage Ht chunk into buf
        *(uint4*)&ht_lds[buf][th][jh] = ch0;
        *(uint4*)&ht_lds[buf][th + 32][jh] = ch1;

        // compute p (bf16) into buf + accumulate register row-sums
        {
            const int* av0 = (const int*)&ca0;
            const int* av1 = (const int*)&ca1;
            const float* s2v = &s2sh[c * BN + jg];
            unsigned short qa[4], qb[4];
            #pragma unroll
            for (int jj = 0; jj < 4; ++jj) {
                float s2x = s2v[jj];
                float eA = fmaxf(s1a + s2x, 0.f);
                float pA = (av0[jj] > 0) ? __expf(eA - Ma) : 0.f;
                qa[jj] = f2bf(pA);
                psA += bf2f(qa[jj]);
                float eB = fmaxf(s1b + s2x, 0.f);
                float pB = (av1[jj] > 0) ? __expf(eB - Mb) : 0.f;
                qb[jj] = f2bf(pB);
                psB += bf2f(qb[jj]);
            }
            *(ushort4*)&p_lds[buf][li][jg]      = make_ushort4(qa[0], qa[1], qa[2], qa[3]);
            *(ushort4*)&p_lds[buf][li + 16][jg] = make_ushort4(qb[0], qb[1], qb[2], qb[3]);
        }

        __syncthreads();   // writes of buf complete; prior reads of buf^1 done

        // PV MFMA from buf: per wave, 16 rows (ih) x 32 cols (nh), K=64
        #pragma unroll
        for (int ks = 0; ks < 2; ++ks) {
            bf16x8 af  = *(const bf16x8*)&p_lds[buf][ih * 16 + cm][ks * 32 + quad * 8];
            bf16x8 bf0 = *(const bf16x8*)&ht_lds[buf][nh * 32 + cm][ks * 32 + quad * 8];
            bf16x8 bf1 = *(const bf16x8*)&ht_lds[buf][nh * 32 + 16 + cm][ks * 32 + quad * 8];
            acc0 = __builtin_amdgcn_mfma_f32_16x16x32_bf16(af, bf0, acc0, 0, 0, 0);
            acc1 = __builtin_amdgcn_mfma_f32_16x16x32_bf16(af, bf1, acc1, 0, 0, 0);
        }

        ca0 = na0; ca1 = na1; ch0 = nh0; ch1 = nh1;
    }

    // final l reduction: sum psA/psB across the 16 lanes of each quarter-wave
    #pragma unroll
    for (int mk = 1; mk < 16; mk <<= 1) {
        psA += __shfl_xor(psA, mk);
        psB += __shfl_xor(psB, mk);
    }
    if ((tid & 15) == 0) {
        pl[(size_t)js * NN + i0 + li]      = psA;
        pl[(size_t)js * NN + i0 + li + 16] = psB;
    }

    // write partial acc
    #pragma unroll
    for (int reg = 0; reg < 4; ++reg) {
        int irow = i0 + ih * 16 + quad * 4 + reg;
        int n0 = nh * 32 + cm;
        pacc[((size_t)js * NN + irow) * FOUT + n0]      = acc0[reg];
        pacc[((size_t)js * NN + irow) * FOUT + n0 + 16] = acc1[reg];
    }
}

// ---------------------------------------------------------------------------
// Kernel 3: combine j-split partials: out = sum(acc) / sum(l)
// ---------------------------------------------------------------------------
__global__ __launch_bounds__(256) void gat_combine(
    const float* __restrict__ pacc, const float* __restrict__ pl,
    float* __restrict__ out)
{
    int idx = blockIdx.x * 256 + threadIdx.x;   // over NN*FOUT
    int i = idx >> 6;
    float s = 0.f, l = 0.f;
    #pragma unroll
    for (int js = 0; js < JSPLIT; ++js) {
        s += pacc[(size_t)js * NN * FOUT + idx];
        l += pl[(size_t)js * NN + i];
    }
    out[idx] = s / l;
}

// ---------------------------------------------------------------------------
extern "C" void kernel_launch(void* const* d_in, const int* in_sizes, int n_in,
                              void* d_out, int out_size, void* d_ws, size_t ws_size,
                              hipStream_t stream) {
    const float* x   = (const float*)d_in[0];
    const int*   adj = (const int*)d_in[1];
    const float* W   = (const float*)d_in[2];
    const float* a   = (const float*)d_in[3];
    float* out = (float*)d_out;

    char* ws = (char*)d_ws;
    float* s1             = (float*)(ws);                         // 32 KB
    float* s2             = (float*)(ws + 32768);                 // 32 KB
    unsigned int* s2enc   = (unsigned int*)(ws + 65536);          // 4 B (padded to 1 KB)
    unsigned short* Ht    = (unsigned short*)(ws + 66560);        // 1 MiB
    float* pacc           = (float*)(ws + 66560 + 1048576);       // 8 MiB
    float* pl             = (float*)(ws + 66560 + 1048576 + 8388608); // 128 KB

    hipMemsetAsync(s2enc, 0, 4, stream);
    gat_prep<<<NN / BM, 256, 0, stream>>>(x, W, a, s1, s2, Ht, s2enc);
    gat_attn<<<(NN / BM) * JSPLIT, 256, 0, stream>>>(adj, s1, s2, Ht, s2enc, pacc, pl);
    gat_combine<<<NN * FOUT / 256, 256, 0, stream>>>(pacc, pl, out);
}

// Round 3
// 402.119 us; speedup vs baseline: 1.0023x; 1.0009x over previous
//
#include <hip/hip_runtime.h>
#include <cstdint>
#include <cstddef>

#define NN 8192
#define FIN 128
#define FOUT 64
#define BM 32
#define BN 64
#define JSPLIT 8
#define JCH (NN / JSPLIT)     // 1024 columns per block
#define NCHUNK (JCH / BN)     // 16 chunks
#define LDP 72                // padded LDS row (bf16 elems)

typedef __bf16 bf16x8 __attribute__((ext_vector_type(8)));
typedef unsigned short u16x8 __attribute__((ext_vector_type(8)));
typedef float f32x4 __attribute__((ext_vector_type(4)));

__device__ __forceinline__ unsigned short f2bf(float f) {
    unsigned u = __float_as_uint(f);
    u += 0x7FFFu + ((u >> 16) & 1u);   // RNE
    return (unsigned short)(u >> 16);
}
__device__ __forceinline__ float bf2f(unsigned short b) {
    return __uint_as_float(((unsigned)b) << 16);
}

// ---------------------------------------------------------------------------
// Kernel 1: prep (unchanged — correct and small).
// ---------------------------------------------------------------------------
__global__ __launch_bounds__(256) void gat_prep(
    const float* __restrict__ x, const float* __restrict__ W,
    const float* __restrict__ a, float* __restrict__ s1,
    float* __restrict__ s2, unsigned short* __restrict__ Ht,
    unsigned int* __restrict__ s2max_enc)
{
    __shared__ __align__(16) float Wt[FOUT][FIN + 4];
    __shared__ float wa1[FIN], wa2[FIN];
    __shared__ float ash[2 * FOUT];
    __shared__ float s2sh[BM];

    const int tid = threadIdx.x;
    const int i0 = blockIdx.x * BM;

    for (int it = 0; it < 32; ++it) {
        int idx = it * 256 + tid;
        int k = idx >> 6, t = idx & 63;
        Wt[t][k] = W[idx];
    }
    if (tid < 2 * FOUT) ash[tid] = a[tid];
    __syncthreads();

    if (tid < FIN) {
        int k = tid;
        float acc = 0.f;
        #pragma unroll 8
        for (int t = 0; t < FOUT; ++t) acc = fmaf(Wt[t][k], ash[t], acc);
        wa1[k] = acc;
    } else {
        int k = tid - FIN;
        float acc = 0.f;
        #pragma unroll 8
        for (int t = 0; t < FOUT; ++t) acc = fmaf(Wt[t][k], ash[FOUT + t], acc);
        wa2[k] = acc;
    }
    __syncthreads();

    {
        int r = tid >> 3;
        int seg = tid & 7;
        const float* xp = x + (size_t)(i0 + r) * FIN + seg * 16;
        float d1 = 0.f, d2 = 0.f;
        #pragma unroll
        for (int m = 0; m < 16; ++m) {
            float xv = xp[m];
            d1 = fmaf(xv, wa1[seg * 16 + m], d1);
            d2 = fmaf(xv, wa2[seg * 16 + m], d2);
        }
        #pragma unroll
        for (int mk = 1; mk < 8; mk <<= 1) {
            d1 += __shfl_xor(d1, mk);
            d2 += __shfl_xor(d2, mk);
        }
        if (seg == 0) {
            s1[i0 + r] = d1;
            s2[i0 + r] = d2;
            s2sh[r] = d2;
        }
    }

    {
        const int lane = tid & 63;
        const int wv = tid >> 6;
        const int ih = wv & 1, nh = wv >> 1;
        const int m = lane & 15, quad = lane >> 4;
        f32x4 hacc0 = {0.f, 0.f, 0.f, 0.f};
        f32x4 hacc1 = {0.f, 0.f, 0.f, 0.f};
        const float* xrow = x + (size_t)(i0 + ih * 16 + m) * FIN + quad * 8;
        #pragma unroll
        for (int ks = 0; ks < 4; ++ks) {
            const float* xp = xrow + ks * 32;
            u16x8 ua;
            #pragma unroll
            for (int jj = 0; jj < 8; ++jj) ua[jj] = f2bf(xp[jj]);
            bf16x8 af = __builtin_bit_cast(bf16x8, ua);
            {
                const float* wp = &Wt[nh * 32 + m][ks * 32 + quad * 8];
                u16x8 ub;
                #pragma unroll
                for (int jj = 0; jj < 8; ++jj) ub[jj] = f2bf(wp[jj]);
                bf16x8 bfr = __builtin_bit_cast(bf16x8, ub);
                hacc0 = __builtin_amdgcn_mfma_f32_16x16x32_bf16(af, bfr, hacc0, 0, 0, 0);
            }
            {
                const float* wp = &Wt[nh * 32 + 16 + m][ks * 32 + quad * 8];
                u16x8 ub;
                #pragma unroll
                for (int jj = 0; jj < 8; ++jj) ub[jj] = f2bf(wp[jj]);
                bf16x8 bfr = __builtin_bit_cast(bf16x8, ub);
                hacc1 = __builtin_amdgcn_mfma_f32_16x16x32_bf16(af, bfr, hacc1, 0, 0, 0);
            }
        }
        #pragma unroll
        for (int reg = 0; reg < 4; ++reg) {
            int irow = i0 + ih * 16 + quad * 4 + reg;
            int t0 = nh * 32 + m;
            Ht[(size_t)t0 * NN + irow] = f2bf(hacc0[reg]);
            Ht[(size_t)(t0 + 16) * NN + irow] = f2bf(hacc1[reg]);
        }
    }
    __syncthreads();
    if (tid == 0) {
        float mx = s2sh[0];
        #pragma unroll
        for (int r = 1; r < BM; ++r) mx = fmaxf(mx, s2sh[r]);
        unsigned ub = __float_as_uint(mx);
        unsigned enc = (ub & 0x80000000u) ? ~ub : (ub | 0x80000000u);
        atomicMax(s2max_enc, enc);
    }
}

// ---------------------------------------------------------------------------
// Kernel 2: fused masked-softmax + PV matmul.
// R3: Ht B-fragments loaded DIRECTLY from global (L2-resident, no LDS
// staging), JSPLIT=8 (2048 blocks), LDS ~13.6 KB, launch_bounds(256,6)
// -> target 6 waves/SIMD for latency hiding of the barrier vmcnt drain.
// ---------------------------------------------------------------------------
__global__ __launch_bounds__(256, 6) void gat_attn(
    const int* __restrict__ adj, const float* __restrict__ s1,
    const float* __restrict__ s2, const unsigned short* __restrict__ Ht,
    const unsigned int* __restrict__ s2max_enc,
    float* __restrict__ pacc, float* __restrict__ pl)
{
    __shared__ __align__(16) unsigned short p_lds[2][BM][LDP];   // 9.2 KB
    __shared__ __align__(16) float s2sh[JCH];                    // 4 KB
    __shared__ float s1v[BM], Mv[BM];

    const int tid = threadIdx.x;
    const int bx = blockIdx.x;
    const int r = bx >> 3;
    const int js = bx & 7;
    const int i0 = r * BM;
    const int j0 = js * JCH;

    const int li = tid >> 4;          // 0..15 (adj row within pass)
    const int jg = (tid & 15) * 4;    // adj col group

    const int* adjp0 = adj + (size_t)(i0 + li) * NN + j0 + jg;
    const int* adjp1 = adjp0 + 16 * NN;

    // prologue adj loads (chunk 0)
    int4 ca0 = *(const int4*)adjp0;
    int4 ca1 = *(const int4*)adjp1;

    const int lane = tid & 63;
    const int wv = tid >> 6;
    const int ih = wv & 1, nh = wv >> 1;
    const int cm = lane & 15, quad = lane >> 4;

    // B-fragment base: row t = nh*32+cm (and +16), col j0 + quad*8
    const unsigned short* htb0 = Ht + (size_t)(nh * 32 + cm) * NN + j0 + quad * 8;
    const unsigned short* htb1 = htb0 + (size_t)16 * NN;

    // stage s2 strip + per-row s1/M
    {
        int idx = tid * 4;
        *(float4*)&s2sh[idx] = *(const float4*)(s2 + j0 + idx);
        unsigned u = *s2max_enc;
        float S2MAX = (u & 0x80000000u) ? __uint_as_float(u ^ 0x80000000u)
                                        : __uint_as_float(~u);
        if (tid < BM) {
            float s = s1[i0 + tid];
            s1v[tid] = s;
            Mv[tid] = fmaxf(0.f, s + S2MAX);  // upper bound of row max of e
        }
    }
    __syncthreads();

    f32x4 acc0 = {0.f, 0.f, 0.f, 0.f};
    f32x4 acc1 = {0.f, 0.f, 0.f, 0.f};
    float psA = 0.f, psB = 0.f;       // deferred l partial sums

    const float s1a = s1v[li], Ma = Mv[li];
    const float s1b = s1v[li + 16], Mb = Mv[li + 16];

    for (int c = 0; c < NCHUNK; ++c) {
        const int buf = c & 1;

        // issue this chunk's Ht B-fragments (L2-resident) — consumed post-barrier
        bf16x8 b00 = *(const bf16x8*)(htb0 + c * BN);           // ks=0, t half 0
        bf16x8 b01 = *(const bf16x8*)(htb1 + c * BN);           // ks=0, t half 1
        bf16x8 b10 = *(const bf16x8*)(htb0 + c * BN + 32);      // ks=1, t half 0
        bf16x8 b11 = *(const bf16x8*)(htb1 + c * BN + 32);      // ks=1, t half 1

        // issue next chunk's adj (HBM)
        const int cn = (c + 1 < NCHUNK) ? (c + 1) : c;
        int4 na0 = *(const int4*)(adjp0 + cn * BN);
        int4 na1 = *(const int4*)(adjp1 + cn * BN);

        // compute p (bf16) into buf + accumulate register row-sums
        {
            const int* av0 = (const int*)&ca0;
            const int* av1 = (const int*)&ca1;
            const float* s2v = &s2sh[c * BN + jg];
            unsigned short qa[4], qb[4];
            #pragma unroll
            for (int jj = 0; jj < 4; ++jj) {
                float s2x = s2v[jj];
                float eA = fmaxf(s1a + s2x, 0.f);
                float pA = (av0[jj] > 0) ? __expf(eA - Ma) : 0.f;
                qa[jj] = f2bf(pA);
                psA += bf2f(qa[jj]);
                float eB = fmaxf(s1b + s2x, 0.f);
                float pB = (av1[jj] > 0) ? __expf(eB - Mb) : 0.f;
                qb[jj] = f2bf(pB);
                psB += bf2f(qb[jj]);
            }
            *(ushort4*)&p_lds[buf][li][jg]      = make_ushort4(qa[0], qa[1], qa[2], qa[3]);
            *(ushort4*)&p_lds[buf][li + 16][jg] = make_ushort4(qb[0], qb[1], qb[2], qb[3]);
        }

        __syncthreads();   // p_lds[buf] visible; also drains vm loads above

        // PV MFMA from buf: per wave, 16 rows (ih) x 32 cols (nh), K=64
        {
            bf16x8 af0 = *(const bf16x8*)&p_lds[buf][ih * 16 + cm][quad * 8];
            bf16x8 af1 = *(const bf16x8*)&p_lds[buf][ih * 16 + cm][32 + quad * 8];
            acc0 = __builtin_amdgcn_mfma_f32_16x16x32_bf16(af0, b00, acc0, 0, 0, 0);
            acc1 = __builtin_amdgcn_mfma_f32_16x16x32_bf16(af0, b01, acc1, 0, 0, 0);
            acc0 = __builtin_amdgcn_mfma_f32_16x16x32_bf16(af1, b10, acc0, 0, 0, 0);
            acc1 = __builtin_amdgcn_mfma_f32_16x16x32_bf16(af1, b11, acc1, 0, 0, 0);
        }

        ca0 = na0; ca1 = na1;
    }

    // final l reduction: sum psA/psB across the 16 lanes of each quarter-wave
    #pragma unroll
    for (int mk = 1; mk < 16; mk <<= 1) {
        psA += __shfl_xor(psA, mk);
        psB += __shfl_xor(psB, mk);
    }
    if ((tid & 15) == 0) {
        pl[(size_t)js * NN + i0 + li]      = psA;
        pl[(size_t)js * NN + i0 + li + 16] = psB;
    }

    // write partial acc
    #pragma unroll
    for (int reg = 0; reg < 4; ++reg) {
        int irow = i0 + ih * 16 + quad * 4 + reg;
        int n0 = nh * 32 + cm;
        pacc[((size_t)js * NN + irow) * FOUT + n0]      = acc0[reg];
        pacc[((size_t)js * NN + irow) * FOUT + n0 + 16] = acc1[reg];
    }
}

// ---------------------------------------------------------------------------
// Kernel 3: combine j-split partials: out = sum(acc) / sum(l)
// ---------------------------------------------------------------------------
__global__ __launch_bounds__(256) void gat_combine(
    const float* __restrict__ pacc, const float* __restrict__ pl,
    float* __restrict__ out)
{
    int idx = blockIdx.x * 256 + threadIdx.x;   // over NN*FOUT
    int i = idx >> 6;
    float s = 0.f, l = 0.f;
    #pragma unroll
    for (int js = 0; js < JSPLIT; ++js) {
        s += pacc[(size_t)js * NN * FOUT + idx];
        l += pl[(size_t)js * NN + i];
    }
    out[idx] = s / l;
}

// ---------------------------------------------------------------------------
extern "C" void kernel_launch(void* const* d_in, const int* in_sizes, int n_in,
                              void* d_out, int out_size, void* d_ws, size_t ws_size,
                              hipStream_t stream) {
    const float* x   = (const float*)d_in[0];
    const int*   adj = (const int*)d_in[1];
    const float* W   = (const float*)d_in[2];
    const float* a   = (const float*)d_in[3];
    float* out = (float*)d_out;

    char* ws = (char*)d_ws;
    float* s1             = (float*)(ws);                         // 32 KB
    float* s2             = (float*)(ws + 32768);                 // 32 KB
    unsigned int* s2enc   = (unsigned int*)(ws + 65536);          // 4 B (padded to 1 KB)
    unsigned short* Ht    = (unsigned short*)(ws + 66560);        // 1 MiB
    float* pacc           = (float*)(ws + 66560 + 1048576);       // 16 MiB (JSPLIT=8)
    float* pl             = (float*)(ws + 66560 + 1048576 + 16777216); // 256 KB

    hipMemsetAsync(s2enc, 0, 4, stream);
    gat_prep<<<NN / BM, 256, 0, stream>>>(x, W, a, s1, s2, Ht, s2enc);
    gat_attn<<<(NN / BM) * JSPLIT, 256, 0, stream>>>(adj, s1, s2, Ht, s2enc, pacc, pl);
    gat_combine<<<NN * FOUT / 256, 256, 0, stream>>>(pacc, pl, out);
}